// Round 14
// baseline (1357.919 us; speedup 1.0000x reference)
//
#include <hip/hip_runtime.h>

typedef __attribute__((ext_vector_type(4))) float f4;
typedef __attribute__((ext_vector_type(8))) short s8v;
typedef __attribute__((ext_vector_type(4))) short s4v;

__device__ __forceinline__ short f2bf(float f) {
  union { float f; unsigned int u; } v; v.f = f;
  unsigned int u = v.u;
  unsigned int r = 0x7fffu + ((u >> 16) & 1u);
  return (short)((u + r) >> 16);
}

__device__ __forceinline__ void glds16(const void* g, void* l) {
  __builtin_amdgcn_global_load_lds((const __attribute__((address_space(1))) void*)g,
                                   (__attribute__((address_space(3))) void*)l, 16, 0, 0);
}

// ---------------------------------------------------------------------------
// Pipelined bf16 GEMM (T3+T4): C = op(A @ Bt^T). A:(M,K), Bt:(N,K) bf16
// row-major. 128x128 tile, BK=64, 256 thr = 4 waves of 64x64.
// 2 LDS buffers (64KB; 68KB total for VT epilogue) -> 2 blocks/CU.
// Full-tile stage + counted vmcnt(8) (never 0 in loop), swapped-operand MFMA,
// LDS-staged full-line epilogue.
// BIAS: 0 none, 1 per-col, 2 per-row.
// VT: blocks with bn0 >= vtoff write their tile TRANSPOSED (bf16) to Cvt
//     via a transposed-LDS layout (Et[col*132+row], 2-way banks = free).
// ---------------------------------------------------------------------------
template<int BIAS, int RES, int RELU, int OF32, int OBF, int VT>
__global__ __launch_bounds__(256) void gemmp(
    const unsigned short* __restrict__ A, const unsigned short* __restrict__ Bt,
    const float* __restrict__ bias, const float* __restrict__ bias2,
    const float* __restrict__ res,
    float* __restrict__ Cf, unsigned short* __restrict__ Cb,
    unsigned short* __restrict__ Cvt, int vtoff, int ldvt,
    int lda, int ldb, int ldc, int ldcb, int ldr, int nk,
    long sA, long sB, long sC, long sCb, long sR, long sBias, long sVt) {
  __shared__ __align__(1024) char lds[69632];
  int tid = threadIdx.x;
  int bx = blockIdx.x, by = blockIdx.y, bz = blockIdx.z;
  int bm0 = by * 128, bn0 = bx * 128;
  const char* Ag = (const char*)(A + bz * sA);
  const char* Bg = (const char*)(Bt + bz * sB);
  if (BIAS) bias += bz * sBias;
  int w = tid >> 6, lane = tid & 63;
  int sr = tid >> 3;                       // 0..31 staging row within 32-row panel
  int skb = ((tid & 7) ^ (sr & 7)) << 4;   // inverse-swizzled source k-byte
  size_t la2 = (size_t)lda * 2, lb2 = (size_t)ldb * 2;
  char* b0 = lds;
  char* b1 = lds + 32768;
  int wm = (w >> 1) * 64, wn = (w & 1) * 64;
  int rb = lane & 15;
  int kx = (lane & 7) << 4;                // read-side swizzle
  int kb0 = (lane >> 4) << 4;
  f4 acc[4][4] = {};

  auto stage = [&](char* buf, int kt) {
    size_t ka = (size_t)kt * 128 + skb;
    glds16(Ag + (size_t)(bm0 + sr) * la2 + ka,      buf + w * 1024);
    glds16(Ag + (size_t)(bm0 + 32 + sr) * la2 + ka, buf + 4096 + w * 1024);
    glds16(Ag + (size_t)(bm0 + 64 + sr) * la2 + ka, buf + 8192 + w * 1024);
    glds16(Ag + (size_t)(bm0 + 96 + sr) * la2 + ka, buf + 12288 + w * 1024);
    glds16(Bg + (size_t)(bn0 + sr) * lb2 + ka,      buf + 16384 + w * 1024);
    glds16(Bg + (size_t)(bn0 + 32 + sr) * lb2 + ka, buf + 20480 + w * 1024);
    glds16(Bg + (size_t)(bn0 + 64 + sr) * lb2 + ka, buf + 24576 + w * 1024);
    glds16(Bg + (size_t)(bn0 + 96 + sr) * lb2 + ka, buf + 28672 + w * 1024);
  };
  auto compute = [&](const char* buf) {
    const char* Ar = buf + (wm + rb) * 128;
    const char* Br = buf + 16384 + (wn + rb) * 128;
#pragma unroll
    for (int ks = 0; ks < 2; ++ks) {
      int kb = (kb0 + ks * 64) ^ kx;
      s8v a[4], b[4];
#pragma unroll
      for (int i = 0; i < 4; ++i) a[i] = *(const s8v*)(Ar + i * 2048 + kb);
#pragma unroll
      for (int j = 0; j < 4; ++j) b[j] = *(const s8v*)(Br + j * 2048 + kb);
      __builtin_amdgcn_s_setprio(1);
#pragma unroll
      for (int i = 0; i < 4; ++i)
#pragma unroll
        for (int j = 0; j < 4; ++j)
          acc[i][j] = __builtin_amdgcn_mfma_f32_16x16x32_bf16(b[j], a[i], acc[i][j], 0, 0, 0);
      __builtin_amdgcn_s_setprio(0);
    }
  };

  stage(b0, 0);
  for (int t = 0; t < nk - 1; ++t) {
    stage(b1, t + 1);
    asm volatile("s_waitcnt vmcnt(8)" ::: "memory");  // tile t arrived; t+1 in flight
    __builtin_amdgcn_s_barrier();
    __builtin_amdgcn_sched_barrier(0);
    compute(b0);
    __builtin_amdgcn_s_barrier();
    char* tp = b0; b0 = b1; b1 = tp;
  }
  asm volatile("s_waitcnt vmcnt(0)" ::: "memory");
  __builtin_amdgcn_s_barrier();
  __builtin_amdgcn_sched_barrier(0);
  compute(b0);

  __syncthreads();
  if (VT && bn0 >= vtoff) {
    // transposed LDS layout: Et[col*132 + row] (pad 4 -> 2-way banks, free)
    float* Et = (float*)lds;
#pragma unroll
    for (int i = 0; i < 4; ++i) {
      int lr = wm + i * 16 + (lane & 15);
#pragma unroll
      for (int j = 0; j < 4; ++j) {
        int col0 = wn + j * 16 + ((lane >> 4) << 2);
#pragma unroll
        for (int c = 0; c < 4; ++c) Et[(col0 + c) * 132 + lr] = acc[i][j][c];
      }
    }
    __syncthreads();
    unsigned short* Vp = Cvt + bz * sVt;
    int hb = bn0 - vtoff;
#pragma unroll
    for (int p = 0; p < 16; ++p) {
      int fi = p * 256 + tid;
      int h = fi >> 5, m4 = (fi & 31) * 4;
      f4 v = *(const f4*)&Et[h * 132 + m4];
      float bb = (BIAS == 1) ? bias[bn0 + h] : 0.f;
      s4v o;
      o[0] = f2bf(v[0] + bb); o[1] = f2bf(v[1] + bb);
      o[2] = f2bf(v[2] + bb); o[3] = f2bf(v[3] + bb);
      *(s4v*)(Vp + (size_t)(hb + h) * ldvt + bm0 + m4) = o;
    }
  } else {
    float* E = (float*)lds;
#pragma unroll
    for (int i = 0; i < 4; ++i) {
      int lr = wm + i * 16 + (lane & 15);
      int sw = (lr & 7) << 2;
#pragma unroll
      for (int j = 0; j < 4; ++j) {
        int col = wn + j * 16 + ((lane >> 4) << 2);
        *(f4*)&E[lr * 128 + (col ^ sw)] = acc[i][j];
      }
    }
    __syncthreads();
    float* Cfp = Cf + bz * sC;
    unsigned short* Cbp = Cb + bz * sCb;
    const float* Rp = res + bz * sR;
#pragma unroll
    for (int p = 0; p < 16; ++p) {
      int fi = p * 256 + tid;
      int row = fi >> 5, c4 = fi & 31;
      f4 v = *(const f4*)&E[row * 128 + ((c4 ^ (row & 7)) << 2)];
      int rr = bm0 + row;
      int col = bn0 + c4 * 4;
      if (BIAS == 1) { v[0] += bias[col]; v[1] += bias[col+1]; v[2] += bias[col+2]; v[3] += bias[col+3]; }
      if (BIAS == 2) { float bb = bias[rr]; v[0] += bb; v[1] += bb; v[2] += bb; v[3] += bb; }
      if (RELU) { v[0]=fmaxf(v[0],0.f); v[1]=fmaxf(v[1],0.f); v[2]=fmaxf(v[2],0.f); v[3]=fmaxf(v[3],0.f); }
      if (RES) { f4 rv = *(const f4*)(Rp + (size_t)rr * ldr + col); v[0]+=rv[0]; v[1]+=rv[1]; v[2]+=rv[2]; v[3]+=rv[3]; }
      if (OF32) *(f4*)(Cfp + (size_t)rr * ldc + col) = v;
      if (OBF) {
        s4v o; o[0]=f2bf(v[0]); o[1]=f2bf(v[1]); o[2]=f2bf(v[2]); o[3]=f2bf(v[3]);
        *(s4v*)(Cbp + (size_t)rr * ldcb + col) = o;
      }
    }
  }
}

// ---------------------------------------------------------------------------
// 64x64-tile batched GEMM (scores), 1-ahead counted-vmcnt pipeline:
// 2 LDS buffers (32KB), vmcnt(4) main loop.
// ---------------------------------------------------------------------------
template<int RES, int OF32, int OBF>
__global__ __launch_bounds__(256) void gemm64(
    const unsigned short* __restrict__ A, const unsigned short* __restrict__ Bt,
    const float* __restrict__ res,
    float* __restrict__ Cf, unsigned short* __restrict__ Cb,
    int lda, int ldb, int ldc, int ldcb, int ldr, int nk,
    long sA, long sB, long sC, long sCb, long sR) {
  __shared__ __align__(1024) char smem[32768];
  int tid = threadIdx.x;
  int bx = blockIdx.x, by = blockIdx.y, bz = blockIdx.z;
  int bm0 = by * 64, bn0 = bx * 64;
  const char* Ag = (const char*)(A + bz * sA);
  const char* Bg = (const char*)(Bt + bz * sB);
  int w = tid >> 6, lane = tid & 63;
  int sr = tid >> 3;
  int skb = ((tid & 7) ^ (sr & 7)) << 4;
  size_t la2 = (size_t)lda * 2, lb2 = (size_t)ldb * 2;
  char* b0 = smem;
  char* b1 = smem + 16384;
  int wm = (w >> 1) * 32, wn = (w & 1) * 32;
  int rb = lane & 15;
  int kx = (lane & 7) << 4;
  int kb0 = (lane >> 4) << 4;
  f4 acc[2][2] = {};

  auto stage = [&](char* buf, int kt) {
    size_t ka = (size_t)kt * 128 + skb;
    glds16(Ag + (size_t)(bm0 + sr) * la2 + ka,      buf + w * 1024);
    glds16(Ag + (size_t)(bm0 + 32 + sr) * la2 + ka, buf + 4096 + w * 1024);
    glds16(Bg + (size_t)(bn0 + sr) * lb2 + ka,      buf + 8192 + w * 1024);
    glds16(Bg + (size_t)(bn0 + 32 + sr) * lb2 + ka, buf + 12288 + w * 1024);
  };
  auto compute = [&](const char* buf) {
    const char* Ar = buf + (wm + rb) * 128;
    const char* Br = buf + 8192 + (wn + rb) * 128;
#pragma unroll
    for (int ks = 0; ks < 2; ++ks) {
      int kb = (kb0 + ks * 64) ^ kx;
      s8v a[2], b[2];
#pragma unroll
      for (int i = 0; i < 2; ++i) a[i] = *(const s8v*)(Ar + i * 2048 + kb);
#pragma unroll
      for (int j = 0; j < 2; ++j) b[j] = *(const s8v*)(Br + j * 2048 + kb);
      __builtin_amdgcn_s_setprio(1);
#pragma unroll
      for (int i = 0; i < 2; ++i)
#pragma unroll
        for (int j = 0; j < 2; ++j)
          acc[i][j] = __builtin_amdgcn_mfma_f32_16x16x32_bf16(b[j], a[i], acc[i][j], 0, 0, 0);
      __builtin_amdgcn_s_setprio(0);
    }
  };

  stage(b0, 0);
  for (int t = 0; t < nk - 1; ++t) {
    stage(b1, t + 1);
    asm volatile("s_waitcnt vmcnt(4)" ::: "memory");
    __builtin_amdgcn_s_barrier();
    __builtin_amdgcn_sched_barrier(0);
    compute(b0);
    __builtin_amdgcn_s_barrier();
    char* tp = b0; b0 = b1; b1 = tp;
  }
  asm volatile("s_waitcnt vmcnt(0)" ::: "memory");
  __builtin_amdgcn_s_barrier();
  __builtin_amdgcn_sched_barrier(0);
  compute(b0);

  float* Cfp = Cf + bz * sC;
  unsigned short* Cbp = Cb + bz * sCb;
  const float* Rp = res + bz * sR;
  float* E = (float*)smem;
  __syncthreads();
#pragma unroll
  for (int i = 0; i < 2; ++i) {
    int lr = wm + i * 16 + (lane & 15);
    int sw = (lr & 7) << 2;
#pragma unroll
    for (int j = 0; j < 2; ++j) {
      int col = wn + j * 16 + ((lane >> 4) << 2);
      *(f4*)&E[lr * 64 + (col ^ sw)] = acc[i][j];
    }
  }
  __syncthreads();
#pragma unroll
  for (int p = 0; p < 4; ++p) {
    int fi = p * 256 + tid;
    int row = fi >> 4, c4 = fi & 15;
    f4 v = *(const f4*)&E[row * 64 + ((c4 ^ (row & 7)) << 2)];
    int rr = bm0 + row;
    int col = bn0 + c4 * 4;
    if (RES) { f4 rv = *(const f4*)(Rp + (size_t)rr * ldr + col); v[0]+=rv[0]; v[1]+=rv[1]; v[2]+=rv[2]; v[3]+=rv[3]; }
    if (OF32) *(f4*)(Cfp + (size_t)rr * ldc + col) = v;
    if (OBF) {
      s4v o; o[0]=f2bf(v[0]); o[1]=f2bf(v[1]); o[2]=f2bf(v[2]); o[3]=f2bf(v[3]);
      *(s4v*)(Cbp + (size_t)rr * ldcb + col) = o;
    }
  }
}

// ---------------------------------------------------------------------------
// Deep-pipelined logits GEMM: C(4096,32000) = A(4096,1024) @ Bt(32000,1024)^T
// + bias. BM=256 BN=64 BK=64, 512 thr (8 waves, 4Mx2N of 64x32).
// 2 LDS buffers (80KB) -> 2 blocks/CU; 1-ahead counted vmcnt(5);
// 4x2 XCD chunking; nt-store epilogue.
// ---------------------------------------------------------------------------
__global__ __launch_bounds__(512) void gemm_logits(
    const unsigned short* __restrict__ A, const unsigned short* __restrict__ Bt,
    const float* __restrict__ bias, float* __restrict__ C) {
  __shared__ __align__(1024) char lds[81920];
  const int ldc = 32000, nk = 16;
  int tid = threadIdx.x;
  int w = tid >> 6, lane = tid & 63;
  // 4x2 XCD chunking over 8000 blocks (500 bx x 16 by)
  int id = blockIdx.y * 500 + blockIdx.x;
  int k = id & 7, j = id >> 3;             // XCD k, sequence j in [0,1000)
  int by = ((k >> 1) << 2) + (j & 3);
  int bx = (k & 1) * 250 + (j >> 2);
  int bm0 = by * 256, bn0 = bx * 64;
  const size_t ld2 = 2048;
  const char* Ag = (const char*)A;
  const char* Bg = (const char*)Bt;
  int srow = (w << 3) + (lane >> 3);                       // 0..63
  size_t ska = (size_t)(((lane & 7) ^ (lane >> 3)) << 4);
  char* bf0 = lds;
  char* bf1 = lds + 40960;
  int wm = (w >> 1) * 64;   // 4 M groups of 64
  int wn = (w & 1) * 32;    // 2 N groups of 32
  int rsel = lane & 15;
  int kx = (lane & 7) << 4;
  int kb0 = (lane >> 4) << 4;
  f4 acc[4][2] = {};

  auto stage = [&](char* buf, int kt) {
    size_t ka = (size_t)kt * 128 + ska;
    glds16(Ag + (size_t)(bm0 + srow) * ld2 + ka,       buf + w * 1024);
    glds16(Ag + (size_t)(bm0 + 64 + srow) * ld2 + ka,  buf + 8192 + w * 1024);
    glds16(Ag + (size_t)(bm0 + 128 + srow) * ld2 + ka, buf + 16384 + w * 1024);
    glds16(Ag + (size_t)(bm0 + 192 + srow) * ld2 + ka, buf + 24576 + w * 1024);
    glds16(Bg + (size_t)(bn0 + srow) * ld2 + ka,       buf + 32768 + w * 1024);
  };
  auto phase = [&](const char* buf, int ks) {
    const char* Ab = buf + (wm + rsel) * 128;
    const char* Bb = buf + 32768 + (wn + rsel) * 128;
    int kb = (kb0 + ks * 64) ^ kx;
    s8v a0 = *(const s8v*)(Ab + kb);
    s8v a1 = *(const s8v*)(Ab + 2048 + kb);
    s8v a2 = *(const s8v*)(Ab + 4096 + kb);
    s8v a3 = *(const s8v*)(Ab + 6144 + kb);
    s8v q0 = *(const s8v*)(Bb + kb);
    s8v q1 = *(const s8v*)(Bb + 2048 + kb);
    __builtin_amdgcn_s_setprio(1);
    acc[0][0] = __builtin_amdgcn_mfma_f32_16x16x32_bf16(q0, a0, acc[0][0], 0, 0, 0);
    acc[0][1] = __builtin_amdgcn_mfma_f32_16x16x32_bf16(q1, a0, acc[0][1], 0, 0, 0);
    acc[1][0] = __builtin_amdgcn_mfma_f32_16x16x32_bf16(q0, a1, acc[1][0], 0, 0, 0);
    acc[1][1] = __builtin_amdgcn_mfma_f32_16x16x32_bf16(q1, a1, acc[1][1], 0, 0, 0);
    acc[2][0] = __builtin_amdgcn_mfma_f32_16x16x32_bf16(q0, a2, acc[2][0], 0, 0, 0);
    acc[2][1] = __builtin_amdgcn_mfma_f32_16x16x32_bf16(q1, a2, acc[2][1], 0, 0, 0);
    acc[3][0] = __builtin_amdgcn_mfma_f32_16x16x32_bf16(q0, a3, acc[3][0], 0, 0, 0);
    acc[3][1] = __builtin_amdgcn_mfma_f32_16x16x32_bf16(q1, a3, acc[3][1], 0, 0, 0);
    __builtin_amdgcn_s_setprio(0);
  };

  stage(bf0, 0);
  for (int t = 0; t < nk - 1; ++t) {
    stage(bf1, t + 1);
    asm volatile("s_waitcnt vmcnt(5)" ::: "memory");
    __builtin_amdgcn_s_barrier();
    __builtin_amdgcn_sched_barrier(0);
    phase(bf0, 0);
    phase(bf0, 1);
    __builtin_amdgcn_s_barrier();
    char* tp = bf0; bf0 = bf1; bf1 = tp;
  }
  asm volatile("s_waitcnt vmcnt(0)" ::: "memory");
  __builtin_amdgcn_s_barrier();
  __builtin_amdgcn_sched_barrier(0);
  phase(bf0, 0);
  phase(bf0, 1);

  // epilogue: acc -> LDS 256x64 f32 (swizzled, 64KB) -> nt f4 streams
  float* E = (float*)lds;
  __syncthreads();
#pragma unroll
  for (int i = 0; i < 4; ++i) {
    int lr = wm + i * 16 + rsel;
    int sw = (lr & 7) << 2;
#pragma unroll
    for (int j = 0; j < 2; ++j) {
      int col = wn + j * 16 + ((lane >> 4) << 2);
      *(f4*)&E[lr * 64 + (col ^ sw)] = acc[i][j];
    }
  }
  __syncthreads();
#pragma unroll
  for (int p = 0; p < 8; ++p) {
    int fi = p * 512 + tid;
    int row = fi >> 4, c4 = fi & 15;
    f4 v = *(const f4*)&E[row * 64 + ((c4 ^ (row & 7)) << 2)];
    int rr = bm0 + row;
    int col = bn0 + c4 * 4;
    v[0] += bias[col]; v[1] += bias[col+1]; v[2] += bias[col+2]; v[3] += bias[col+3];
    __builtin_nontemporal_store(v, (f4*)(C + (size_t)rr * ldc + col));
  }
}

// 64x64 tile transpose: f32 (rows, cols) -> bf16 (cols, rows)
__device__ __forceinline__ void wtrans_tile(const float* src, unsigned short* dst,
                                            int rows, int cols, int c0, int r0) {
  __shared__ float t[64][65];
  int tx = threadIdx.x & 63, ty = threadIdx.x >> 6;
#pragma unroll
  for (int j = 0; j < 16; ++j) {
    int r = j * 4 + ty;
    t[r][tx] = src[(size_t)(r0 + r) * cols + c0 + tx];
  }
  __syncthreads();
#pragma unroll
  for (int j = 0; j < 16; ++j) {
    int n = j * 4 + ty;
    dst[(size_t)(c0 + n) * rows + r0 + tx] = (unsigned short)f2bf(t[tx][n]);
  }
}

__global__ __launch_bounds__(256) void wtrans_k(const float* __restrict__ src,
                                                unsigned short* __restrict__ dst,
                                                int rows, int cols) {
  wtrans_tile(src, dst, rows, cols, blockIdx.x * 64, blockIdx.y * 64);
}

// All 42 H x H weight transposes in one launch. z = l*7 + wi.
__global__ __launch_bounds__(256) void wtrans_all_k(
    const float* __restrict__ w0, const float* __restrict__ w1,
    const float* __restrict__ w2, const float* __restrict__ w3,
    const float* __restrict__ w4, const float* __restrict__ w5,
    const float* __restrict__ w6, unsigned short* __restrict__ dst) {
  int z = blockIdx.z;
  int l = z / 7, wi = z % 7;
  const float* src;
  switch (wi) {
    case 0: src = w0; break;
    case 1: src = w1; break;
    case 2: src = w2; break;
    case 3: src = w3; break;
    case 4: src = w4; break;
    case 5: src = w5; break;
    default: src = w6; break;
  }
  src += (size_t)l * 1024 * 1024;
  unsigned short* d = dst + (size_t)z * 1024 * 1024;
  wtrans_tile(src, d, 1024, 1024, blockIdx.x * 64, blockIdx.y * 64);
}

__global__ __launch_bounds__(256) void convbf_k(const float* __restrict__ src,
                                                unsigned short* __restrict__ dst, int n4) {
  int i = blockIdx.x * 256 + threadIdx.x;
  if (i >= n4) return;
  f4 f = ((const f4*)src)[i];
  s4v v;
  v[0] = f2bf(f[0]); v[1] = f2bf(f[1]); v[2] = f2bf(f[2]); v[3] = f2bf(f[3]);
  ((s4v*)dst)[i] = v;
}

// Concatenated bias buffers: catb[l] = [bq_s|bk_s|bv_s] (3072), catbc[l] = [bk_c|bv_c] (2048)
__global__ __launch_bounds__(1024) void catb_k(
    const float* __restrict__ bq, const float* __restrict__ bk,
    const float* __restrict__ bv, const float* __restrict__ bkc,
    const float* __restrict__ bvc, float* __restrict__ catb,
    float* __restrict__ catbc) {
  int l = blockIdx.x, t = threadIdx.x;
  size_t o = (size_t)l * 1024 + t;
  catb[(size_t)l * 3072 + t] = bq[o];
  catb[(size_t)l * 3072 + 1024 + t] = bk[o];
  catb[(size_t)l * 3072 + 2048 + t] = bv[o];
  catbc[(size_t)l * 2048 + t] = bkc[o];
  catbc[(size_t)l * 2048 + 1024 + t] = bvc[o];
}

// ---------------------------------------------------------------------------
// Fused softmax + transpose, 32 q-rows per block, 512 threads.
// ---------------------------------------------------------------------------
template<int CAUSAL>
__global__ __launch_bounds__(512) void smt_k(const float* __restrict__ Sf,
                                             float* __restrict__ outT,
                                             unsigned short* __restrict__ Wb) {
  __shared__ float T[32][524];
  int b = blockIdx.y;
  int q0 = blockIdx.x * 32;
  int t = threadIdx.x;
  const float* Sp = Sf + ((size_t)b * 512 + q0) * 512;
#pragma unroll
  for (int j = 0; j < 8; ++j) {
    int idx = t + 512 * j;
    int r = idx >> 7, c4 = idx & 127;
    f4 v = *(const f4*)(Sp + (size_t)r * 512 + c4 * 4);
    *(f4*)&T[r][c4 * 4] = v;
  }
  __syncthreads();
  int w = t >> 6, l = t & 63;
  int r = 4 * w + (l >> 4);
  int l16 = l & 15;
  int q = q0 + r;
  const float scale = 0.03125f;
  float v[32];
#pragma unroll
  for (int j = 0; j < 32; ++j) {
    int k = l16 + 16 * j;
    float x = T[r][k] * scale;
    if (CAUSAL && k > q) x += -1.0e7f;
    v[j] = x;
  }
  float m = v[0];
#pragma unroll
  for (int j = 1; j < 32; ++j) m = fmaxf(m, v[j]);
  m = fmaxf(m, __shfl_xor(m, 1)); m = fmaxf(m, __shfl_xor(m, 2));
  m = fmaxf(m, __shfl_xor(m, 4)); m = fmaxf(m, __shfl_xor(m, 8));
  float s = 0.f;
#pragma unroll
  for (int j = 0; j < 32; ++j) { v[j] = __expf(v[j] - m); s += v[j]; }
  s += __shfl_xor(s, 1); s += __shfl_xor(s, 2);
  s += __shfl_xor(s, 4); s += __shfl_xor(s, 8);
  float inv = 1.0f / s;
#pragma unroll
  for (int j = 0; j < 32; ++j) T[r][l16 + 16 * j] = v[j] * inv;
  __syncthreads();
  float* op = outT + (size_t)b * 512 * 512 + q0;
  int ql = t & 31, kb = t >> 5;
#pragma unroll
  for (int i = 0; i < 32; ++i) {
    int k = kb + 16 * i;
    __builtin_nontemporal_store(T[ql][k], &op[(size_t)k * 512 + ql]);
  }
  unsigned short* wp = Wb + ((size_t)b * 512 + q0) * 512;
#pragma unroll
  for (int i = 0; i < 4; ++i) {
    int rr = 4 * w + i;
    const float* row = &T[rr][l * 8];
    s8v o;
#pragma unroll
    for (int j = 0; j < 8; ++j) o[j] = f2bf(row[j]);
    *(s8v*)(wp + (size_t)rr * 512 + l * 8) = o;
  }
}

__global__ __launch_bounds__(256) void embed_pe_k(const int* __restrict__ ids,
                                                  const float* __restrict__ emb,
                                                  float* __restrict__ ctx,
                                                  unsigned short* __restrict__ ctxb) {
  int row = blockIdx.x;
  int s = row & 511;
  int t = threadIdx.x;
  int id = ids[row];
  f4 e = *(const f4*)(emb + (size_t)id * 1024 + t * 4);
  int j0 = 2 * t, j1 = 2 * t + 1;
  float fr0 = powf(10000.0f, -2.0f * (float)j0 / 1024.0f);
  float fr1 = powf(10000.0f, -2.0f * (float)j1 / 1024.0f);
  float s0, c0, s1, c1;
  sincosf((float)s * fr0, &s0, &c0);
  sincosf((float)s * fr1, &s1, &c1);
  f4 o;
  o[0] = e[0] + s0; o[1] = e[1] + c0; o[2] = e[2] + s1; o[3] = e[3] + c1;
  *(f4*)(ctx + (size_t)row * 1024 + t * 4) = o;
  s4v ob;
  ob[0] = f2bf(o[0]); ob[1] = f2bf(o[1]); ob[2] = f2bf(o[2]); ob[3] = f2bf(o[3]);
  *(s4v*)(ctxb + (size_t)row * 1024 + t * 4) = ob;
}

extern "C" void kernel_launch(void* const* d_in, const int* in_sizes, int n_in,
                              void* d_out, int out_size, void* d_ws, size_t ws_size,
                              hipStream_t stream) {
  const int B = 8, S = 512, H = 1024, V = 32000, L = 6;
  const int M = B * S;  // 4096

  const int* ids = (const int*)d_in[0];
  const float* ann = (const float*)d_in[1];
  const float* emb = (const float*)d_in[3];
  const float* bq_s = (const float*)d_in[5];
  const float* bk_s = (const float*)d_in[7];
  const float* bv_s = (const float*)d_in[9];
  const float* bq_c = (const float*)d_in[11];
  const float* bk_c = (const float*)d_in[13];
  const float* bv_c = (const float*)d_in[15];
  const float* bm = (const float*)d_in[17];
  const float* Wout = (const float*)d_in[18];
  const float* bout = (const float*)d_in[19];
  float* out = (float*)d_out;

  char* ws = (char*)d_ws;
  if (ws_size < ((size_t)164 << 20)) return;
  float* X0 = (float*)ws;                                             // 16MB residual (in-place)
  unsigned short* Xs0 = (unsigned short*)(ws + ((size_t)16 << 20));   // 8MB bf16 ctx slot 0
  unsigned short* Xs1 = (unsigned short*)(ws + ((size_t)24 << 20));   // 8MB bf16 ctx slot 1
  unsigned short* QKbf = (unsigned short*)(ws + ((size_t)32 << 20));  // 16MB (4096,2048)
  unsigned short* Vtbf = (unsigned short*)(ws + ((size_t)48 << 20));  // 8MB (H,4096)
  float* Sbuf = (float*)(ws + ((size_t)56 << 20));                    // 8MB raw scores f32
  unsigned short* Wbf = (unsigned short*)(ws + ((size_t)64 << 20));   // 4MB softmax bf16
  unsigned short* annbf = (unsigned short*)(ws + ((size_t)68 << 20)); // 8MB
  unsigned short* WT = (unsigned short*)(ws + ((size_t)76 << 20));    // 84MB: 42 x (H,H)
  float* catb = (float*)(ws + ((size_t)160 << 20));                   // 72KB (L,3072)
  float* catbc = (float*)(ws + ((size_t)160 << 20) + (96 << 10));     // 48KB (L,2048)
  unsigned short* KcAll = (unsigned short*)d_out;                     // 48MB: 6 x (4096,H)
  unsigned short* VtcAll = (unsigned short*)((char*)d_out + ((size_t)48 << 20)); // 48MB

  size_t enc_off = (size_t)M * V;
  size_t self_off = enc_off + (size_t)L * B * S * S;

  long sQ = (long)S * H;
  long sS = (long)S * S;
  const size_t WSZ = (size_t)H * H;
  const long sW7 = (long)(7 * WSZ);

  embed_pe_k<<<M, 256, 0, stream>>>(ids, emb, X0, Xs0);
  convbf_k<<<(M * H / 4 + 255) / 256, 256, 0, stream>>>(ann, annbf, M * H / 4);
  catb_k<<<L, 1024, 0, stream>>>(bq_s, bk_s, bv_s, bk_c, bv_c, catb, catbc);
  wtrans_all_k<<<dim3(16, 16, 42), 256, 0, stream>>>(
      (const float*)d_in[4], (const float*)d_in[6], (const float*)d_in[8],
      (const float*)d_in[10], (const float*)d_in[12], (const float*)d_in[14],
      (const float*)d_in[16], WT);
  // All-layer cross K|V^T in one launch: (l, 4096, 2048); cols >= 1024 -> VtcAll^T
  gemmp<1, 0, 0, 0, 1, 1><<<dim3(16, 32, 6), 256, 0, stream>>>(
      annbf, WT + 4 * WSZ, catbc, nullptr, nullptr,
      nullptr, KcAll, VtcAll, 1024, M,
      H, H, 0, H, 0, 16,
      0, sW7, 0, (long)M * H, 0, 2048, (long)H * M);

  unsigned short* Xa = Xs0;
  unsigned short* Xb = Xs1;

  for (int l = 0; l < L; ++l) {
    size_t bo = (size_t)l * H;
    unsigned short* WTl = WT + (size_t)l * 7 * WSZ;

    // ---- self attention ----
    // Q|K|V = X @ [Wq Wk Wv] : (4096, 3072); V-cols written transposed -> Vtbf
    gemmp<1, 0, 0, 0, 1, 1><<<dim3(24, 32), 256, 0, stream>>>(
        Xa, WTl, catb + (size_t)l * 3072, nullptr, nullptr,
        nullptr, QKbf, Vtbf, 2048, M,
        H, H, 0, 2048, 0, 16,
        0, 0, 0, 0, 0, 0, 0);
    // raw scores (b,q,k) -> Sbuf
    gemm64<0, 1, 0><<<dim3(8, 8, B), 256, 0, stream>>>(
        QKbf, QKbf + 1024, nullptr, Sbuf, nullptr,
        2048, 2048, S, 0, 0, 16, (long)S * 2048, (long)S * 2048, sS, 0, 0);
    smt_k<1><<<dim3(16, B), 512, 0, stream>>>(
        Sbuf, out + self_off + (size_t)l * B * S * S, Wbf);
    // R1 = X0 + W @ V (in-place f32, 128^2 pipelined) ; bf16 -> Xb
    gemmp<0, 1, 0, 1, 1, 0><<<dim3(8, 4, B), 256, 0, stream>>>(
        Wbf, Vtbf, nullptr, nullptr, X0,
        X0, Xb, nullptr, 0, 0,
        S, M, H, H, H, 8,
        sS, 512, sQ, sQ, sQ, 0, 0);
    // ---- cross attention ----
    gemmp<1, 0, 0, 0, 1, 0><<<dim3(8, 32), 256, 0, stream>>>(
        Xb, WTl + 3 * WSZ, bq_c + bo, nullptr, nullptr,
        nullptr, QKbf, nullptr, 0, 0,
        H, H, 0, 1024, 0, 16,
        0, 0, 0, 0, 0, 0, 0);
    gemm64<0, 1, 0><<<dim3(8, 8, B), 256, 0, stream>>>(
        QKbf, KcAll + (size_t)l * M * H, nullptr, Sbuf, nullptr,
        1024, 1024, S, 0, 0, 16, (long)S * 1024, (long)S * 1024, sS, 0, 0);
    smt_k<0><<<dim3(16, B), 512, 0, stream>>>(
        Sbuf, out + enc_off + (size_t)l * B * S * S, Wbf);
    // R2 = R1 + W @ V (in-place f32, 128^2 pipelined) ; bf16 -> Xa
    gemmp<0, 1, 0, 1, 1, 0><<<dim3(8, 4, B), 256, 0, stream>>>(
        Wbf, VtcAll + (size_t)l * H * M, nullptr, nullptr, X0,
        X0, Xa, nullptr, 0, 0,
        S, M, H, H, H, 8,
        sS, 512, sQ, sQ, sQ, 0, 0);
    // ctx' = R2 + relu(R2 @ Wm + bm) (in-place f32) ; bf16 -> Xb
    gemmp<1, 1, 1, 1, 1, 0><<<dim3(8, 32), 256, 0, stream>>>(
        Xa, WTl + 6 * WSZ, bm + bo, nullptr, X0,
        X0, Xb, nullptr, 0, 0,
        H, H, H, H, H, 16,
        0, 0, 0, 0, 0, 0, 0);
    unsigned short* tb = Xa; Xa = Xb; Xb = tb;
  }

  // WoutT (V, H) bf16 -> overlay WT region (weights no longer needed)
  wtrans_k<<<dim3(V / 64, H / 64), 256, 0, stream>>>(Wout, WT, H, V);
  // logits = ctx @ Wout + bout   (BM=256xBN=64, 2 blocks/CU, nt-store epilogue)
  gemm_logits<<<dim3(500, 16), 512, 0, stream>>>(Xa, WT, bout, out);
}

// Round 15
// 1338.902 us; speedup vs baseline: 1.0142x; 1.0142x over previous
//
#include <hip/hip_runtime.h>

typedef __attribute__((ext_vector_type(4))) float f4;
typedef __attribute__((ext_vector_type(8))) short s8v;
typedef __attribute__((ext_vector_type(4))) short s4v;

__device__ __forceinline__ short f2bf(float f) {
  union { float f; unsigned int u; } v; v.f = f;
  unsigned int u = v.u;
  unsigned int r = 0x7fffu + ((u >> 16) & 1u);
  return (short)((u + r) >> 16);
}

__device__ __forceinline__ void glds16(const void* g, void* l) {
  __builtin_amdgcn_global_load_lds((const __attribute__((address_space(1))) void*)g,
                                   (__attribute__((address_space(3))) void*)l, 16, 0, 0);
}

// ---------------------------------------------------------------------------
// Pipelined bf16 GEMM (T3+T4): C = op(A @ Bt^T). A:(M,K), Bt:(N,K) bf16
// row-major. 128x128 tile, BK=64, 256 thr = 4 waves of 64x64.
// 2 LDS buffers (64KB; 68KB total for VT epilogue) -> 2 blocks/CU.
// Full-tile stage + counted vmcnt(8) (never 0 in loop), swapped-operand MFMA,
// LDS-staged full-line epilogue.
// BIAS: 0 none, 1 per-col, 2 per-row.
// VT: blocks with bn0 >= vtoff write their tile TRANSPOSED (bf16) to Cvt
//     via a transposed-LDS layout (Et[col*132+row], 2-way banks = free).
// ---------------------------------------------------------------------------
template<int BIAS, int RES, int RELU, int OF32, int OBF, int VT>
__global__ __launch_bounds__(256) void gemmp(
    const unsigned short* __restrict__ A, const unsigned short* __restrict__ Bt,
    const float* __restrict__ bias, const float* __restrict__ bias2,
    const float* __restrict__ res,
    float* __restrict__ Cf, unsigned short* __restrict__ Cb,
    unsigned short* __restrict__ Cvt, int vtoff, int ldvt,
    int lda, int ldb, int ldc, int ldcb, int ldr, int nk,
    long sA, long sB, long sC, long sCb, long sR, long sBias, long sVt) {
  __shared__ __align__(1024) char lds[69632];
  int tid = threadIdx.x;
  int bx = blockIdx.x, by = blockIdx.y, bz = blockIdx.z;
  int bm0 = by * 128, bn0 = bx * 128;
  const char* Ag = (const char*)(A + bz * sA);
  const char* Bg = (const char*)(Bt + bz * sB);
  if (BIAS) bias += bz * sBias;
  int w = tid >> 6, lane = tid & 63;
  int sr = tid >> 3;                       // 0..31 staging row within 32-row panel
  int skb = ((tid & 7) ^ (sr & 7)) << 4;   // inverse-swizzled source k-byte
  size_t la2 = (size_t)lda * 2, lb2 = (size_t)ldb * 2;
  char* b0 = lds;
  char* b1 = lds + 32768;
  int wm = (w >> 1) * 64, wn = (w & 1) * 64;
  int rb = lane & 15;
  int kx = (lane & 7) << 4;                // read-side swizzle
  int kb0 = (lane >> 4) << 4;
  f4 acc[4][4] = {};

  auto stage = [&](char* buf, int kt) {
    size_t ka = (size_t)kt * 128 + skb;
    glds16(Ag + (size_t)(bm0 + sr) * la2 + ka,      buf + w * 1024);
    glds16(Ag + (size_t)(bm0 + 32 + sr) * la2 + ka, buf + 4096 + w * 1024);
    glds16(Ag + (size_t)(bm0 + 64 + sr) * la2 + ka, buf + 8192 + w * 1024);
    glds16(Ag + (size_t)(bm0 + 96 + sr) * la2 + ka, buf + 12288 + w * 1024);
    glds16(Bg + (size_t)(bn0 + sr) * lb2 + ka,      buf + 16384 + w * 1024);
    glds16(Bg + (size_t)(bn0 + 32 + sr) * lb2 + ka, buf + 20480 + w * 1024);
    glds16(Bg + (size_t)(bn0 + 64 + sr) * lb2 + ka, buf + 24576 + w * 1024);
    glds16(Bg + (size_t)(bn0 + 96 + sr) * lb2 + ka, buf + 28672 + w * 1024);
  };
  auto compute = [&](const char* buf) {
    const char* Ar = buf + (wm + rb) * 128;
    const char* Br = buf + 16384 + (wn + rb) * 128;
#pragma unroll
    for (int ks = 0; ks < 2; ++ks) {
      int kb = (kb0 + ks * 64) ^ kx;
      s8v a[4], b[4];
#pragma unroll
      for (int i = 0; i < 4; ++i) a[i] = *(const s8v*)(Ar + i * 2048 + kb);
#pragma unroll
      for (int j = 0; j < 4; ++j) b[j] = *(const s8v*)(Br + j * 2048 + kb);
      __builtin_amdgcn_s_setprio(1);
#pragma unroll
      for (int i = 0; i < 4; ++i)
#pragma unroll
        for (int j = 0; j < 4; ++j)
          acc[i][j] = __builtin_amdgcn_mfma_f32_16x16x32_bf16(b[j], a[i], acc[i][j], 0, 0, 0);
      __builtin_amdgcn_s_setprio(0);
    }
  };

  stage(b0, 0);
  for (int t = 0; t < nk - 1; ++t) {
    stage(b1, t + 1);
    asm volatile("s_waitcnt vmcnt(8)" ::: "memory");  // tile t arrived; t+1 in flight
    __builtin_amdgcn_s_barrier();
    __builtin_amdgcn_sched_barrier(0);
    compute(b0);
    __builtin_amdgcn_s_barrier();
    char* tp = b0; b0 = b1; b1 = tp;
  }
  asm volatile("s_waitcnt vmcnt(0)" ::: "memory");
  __builtin_amdgcn_s_barrier();
  __builtin_amdgcn_sched_barrier(0);
  compute(b0);

  __syncthreads();
  if (VT && bn0 >= vtoff) {
    // transposed LDS layout: Et[col*132 + row] (pad 4 -> 2-way banks, free)
    float* Et = (float*)lds;
#pragma unroll
    for (int i = 0; i < 4; ++i) {
      int lr = wm + i * 16 + (lane & 15);
#pragma unroll
      for (int j = 0; j < 4; ++j) {
        int col0 = wn + j * 16 + ((lane >> 4) << 2);
#pragma unroll
        for (int c = 0; c < 4; ++c) Et[(col0 + c) * 132 + lr] = acc[i][j][c];
      }
    }
    __syncthreads();
    unsigned short* Vp = Cvt + bz * sVt;
    int hb = bn0 - vtoff;
#pragma unroll
    for (int p = 0; p < 16; ++p) {
      int fi = p * 256 + tid;
      int h = fi >> 5, m4 = (fi & 31) * 4;
      f4 v = *(const f4*)&Et[h * 132 + m4];
      float bb = (BIAS == 1) ? bias[bn0 + h] : 0.f;
      s4v o;
      o[0] = f2bf(v[0] + bb); o[1] = f2bf(v[1] + bb);
      o[2] = f2bf(v[2] + bb); o[3] = f2bf(v[3] + bb);
      *(s4v*)(Vp + (size_t)(hb + h) * ldvt + bm0 + m4) = o;
    }
  } else {
    float* E = (float*)lds;
#pragma unroll
    for (int i = 0; i < 4; ++i) {
      int lr = wm + i * 16 + (lane & 15);
      int sw = (lr & 7) << 2;
#pragma unroll
      for (int j = 0; j < 4; ++j) {
        int col = wn + j * 16 + ((lane >> 4) << 2);
        *(f4*)&E[lr * 128 + (col ^ sw)] = acc[i][j];
      }
    }
    __syncthreads();
    float* Cfp = Cf + bz * sC;
    unsigned short* Cbp = Cb + bz * sCb;
    const float* Rp = res + bz * sR;
#pragma unroll
    for (int p = 0; p < 16; ++p) {
      int fi = p * 256 + tid;
      int row = fi >> 5, c4 = fi & 31;
      f4 v = *(const f4*)&E[row * 128 + ((c4 ^ (row & 7)) << 2)];
      int rr = bm0 + row;
      int col = bn0 + c4 * 4;
      if (BIAS == 1) { v[0] += bias[col]; v[1] += bias[col+1]; v[2] += bias[col+2]; v[3] += bias[col+3]; }
      if (BIAS == 2) { float bb = bias[rr]; v[0] += bb; v[1] += bb; v[2] += bb; v[3] += bb; }
      if (RELU) { v[0]=fmaxf(v[0],0.f); v[1]=fmaxf(v[1],0.f); v[2]=fmaxf(v[2],0.f); v[3]=fmaxf(v[3],0.f); }
      if (RES) { f4 rv = *(const f4*)(Rp + (size_t)rr * ldr + col); v[0]+=rv[0]; v[1]+=rv[1]; v[2]+=rv[2]; v[3]+=rv[3]; }
      if (OF32) *(f4*)(Cfp + (size_t)rr * ldc + col) = v;
      if (OBF) {
        s4v o; o[0]=f2bf(v[0]); o[1]=f2bf(v[1]); o[2]=f2bf(v[2]); o[3]=f2bf(v[3]);
        *(s4v*)(Cbp + (size_t)rr * ldcb + col) = o;
      }
    }
  }
}

// ---------------------------------------------------------------------------
// 64x64-tile batched GEMM (scores, PV), 1-ahead counted-vmcnt pipeline:
// 2 LDS buffers (32KB), vmcnt(4) main loop. 4 blocks/CU.
// ---------------------------------------------------------------------------
template<int RES, int OF32, int OBF>
__global__ __launch_bounds__(256) void gemm64(
    const unsigned short* __restrict__ A, const unsigned short* __restrict__ Bt,
    const float* __restrict__ res,
    float* __restrict__ Cf, unsigned short* __restrict__ Cb,
    int lda, int ldb, int ldc, int ldcb, int ldr, int nk,
    long sA, long sB, long sC, long sCb, long sR) {
  __shared__ __align__(1024) char smem[32768];
  int tid = threadIdx.x;
  int bx = blockIdx.x, by = blockIdx.y, bz = blockIdx.z;
  int bm0 = by * 64, bn0 = bx * 64;
  const char* Ag = (const char*)(A + bz * sA);
  const char* Bg = (const char*)(Bt + bz * sB);
  int w = tid >> 6, lane = tid & 63;
  int sr = tid >> 3;
  int skb = ((tid & 7) ^ (sr & 7)) << 4;
  size_t la2 = (size_t)lda * 2, lb2 = (size_t)ldb * 2;
  char* b0 = smem;
  char* b1 = smem + 16384;
  int wm = (w >> 1) * 32, wn = (w & 1) * 32;
  int rb = lane & 15;
  int kx = (lane & 7) << 4;
  int kb0 = (lane >> 4) << 4;
  f4 acc[2][2] = {};

  auto stage = [&](char* buf, int kt) {
    size_t ka = (size_t)kt * 128 + skb;
    glds16(Ag + (size_t)(bm0 + sr) * la2 + ka,      buf + w * 1024);
    glds16(Ag + (size_t)(bm0 + 32 + sr) * la2 + ka, buf + 4096 + w * 1024);
    glds16(Bg + (size_t)(bn0 + sr) * lb2 + ka,      buf + 8192 + w * 1024);
    glds16(Bg + (size_t)(bn0 + 32 + sr) * lb2 + ka, buf + 12288 + w * 1024);
  };
  auto compute = [&](const char* buf) {
    const char* Ar = buf + (wm + rb) * 128;
    const char* Br = buf + 8192 + (wn + rb) * 128;
#pragma unroll
    for (int ks = 0; ks < 2; ++ks) {
      int kb = (kb0 + ks * 64) ^ kx;
      s8v a[2], b[2];
#pragma unroll
      for (int i = 0; i < 2; ++i) a[i] = *(const s8v*)(Ar + i * 2048 + kb);
#pragma unroll
      for (int j = 0; j < 2; ++j) b[j] = *(const s8v*)(Br + j * 2048 + kb);
      __builtin_amdgcn_s_setprio(1);
#pragma unroll
      for (int i = 0; i < 2; ++i)
#pragma unroll
        for (int j = 0; j < 2; ++j)
          acc[i][j] = __builtin_amdgcn_mfma_f32_16x16x32_bf16(b[j], a[i], acc[i][j], 0, 0, 0);
      __builtin_amdgcn_s_setprio(0);
    }
  };

  stage(b0, 0);
  for (int t = 0; t < nk - 1; ++t) {
    stage(b1, t + 1);
    asm volatile("s_waitcnt vmcnt(4)" ::: "memory");
    __builtin_amdgcn_s_barrier();
    __builtin_amdgcn_sched_barrier(0);
    compute(b0);
    __builtin_amdgcn_s_barrier();
    char* tp = b0; b0 = b1; b1 = tp;
  }
  asm volatile("s_waitcnt vmcnt(0)" ::: "memory");
  __builtin_amdgcn_s_barrier();
  __builtin_amdgcn_sched_barrier(0);
  compute(b0);

  float* Cfp = Cf + bz * sC;
  unsigned short* Cbp = Cb + bz * sCb;
  const float* Rp = res + bz * sR;
  float* E = (float*)smem;
  __syncthreads();
#pragma unroll
  for (int i = 0; i < 2; ++i) {
    int lr = wm + i * 16 + (lane & 15);
    int sw = (lr & 7) << 2;
#pragma unroll
    for (int j = 0; j < 2; ++j) {
      int col = wn + j * 16 + ((lane >> 4) << 2);
      *(f4*)&E[lr * 64 + (col ^ sw)] = acc[i][j];
    }
  }
  __syncthreads();
#pragma unroll
  for (int p = 0; p < 4; ++p) {
    int fi = p * 256 + tid;
    int row = fi >> 4, c4 = fi & 15;
    f4 v = *(const f4*)&E[row * 64 + ((c4 ^ (row & 7)) << 2)];
    int rr = bm0 + row;
    int col = bn0 + c4 * 4;
    if (RES) { f4 rv = *(const f4*)(Rp + (size_t)rr * ldr + col); v[0]+=rv[0]; v[1]+=rv[1]; v[2]+=rv[2]; v[3]+=rv[3]; }
    if (OF32) *(f4*)(Cfp + (size_t)rr * ldc + col) = v;
    if (OBF) {
      s4v o; o[0]=f2bf(v[0]); o[1]=f2bf(v[1]); o[2]=f2bf(v[2]); o[3]=f2bf(v[3]);
      *(s4v*)(Cbp + (size_t)rr * ldcb + col) = o;
    }
  }
}

// ---------------------------------------------------------------------------
// Deep-pipelined logits GEMM: C(4096,32000) = A(4096,1024) @ Bt(32000,1024)^T
// + bias. BM=256 BN=64 BK=64, 512 thr (8 waves, 4Mx2N of 64x32).
// 2 LDS buffers (80KB) -> 2 blocks/CU; 1-ahead counted vmcnt(5);
// 4x2 XCD chunking; nt-store epilogue.
// ---------------------------------------------------------------------------
__global__ __launch_bounds__(512) void gemm_logits(
    const unsigned short* __restrict__ A, const unsigned short* __restrict__ Bt,
    const float* __restrict__ bias, float* __restrict__ C) {
  __shared__ __align__(1024) char lds[81920];
  const int ldc = 32000, nk = 16;
  int tid = threadIdx.x;
  int w = tid >> 6, lane = tid & 63;
  // 4x2 XCD chunking over 8000 blocks (500 bx x 16 by)
  int id = blockIdx.y * 500 + blockIdx.x;
  int k = id & 7, j = id >> 3;             // XCD k, sequence j in [0,1000)
  int by = ((k >> 1) << 2) + (j & 3);
  int bx = (k & 1) * 250 + (j >> 2);
  int bm0 = by * 256, bn0 = bx * 64;
  const size_t ld2 = 2048;
  const char* Ag = (const char*)A;
  const char* Bg = (const char*)Bt;
  int srow = (w << 3) + (lane >> 3);                       // 0..63
  size_t ska = (size_t)(((lane & 7) ^ (lane >> 3)) << 4);
  char* bf0 = lds;
  char* bf1 = lds + 40960;
  int wm = (w >> 1) * 64;   // 4 M groups of 64
  int wn = (w & 1) * 32;    // 2 N groups of 32
  int rsel = lane & 15;
  int kx = (lane & 7) << 4;
  int kb0 = (lane >> 4) << 4;
  f4 acc[4][2] = {};

  auto stage = [&](char* buf, int kt) {
    size_t ka = (size_t)kt * 128 + ska;
    glds16(Ag + (size_t)(bm0 + srow) * ld2 + ka,       buf + w * 1024);
    glds16(Ag + (size_t)(bm0 + 64 + srow) * ld2 + ka,  buf + 8192 + w * 1024);
    glds16(Ag + (size_t)(bm0 + 128 + srow) * ld2 + ka, buf + 16384 + w * 1024);
    glds16(Ag + (size_t)(bm0 + 192 + srow) * ld2 + ka, buf + 24576 + w * 1024);
    glds16(Bg + (size_t)(bn0 + srow) * ld2 + ka,       buf + 32768 + w * 1024);
  };
  auto phase = [&](const char* buf, int ks) {
    const char* Ab = buf + (wm + rsel) * 128;
    const char* Bb = buf + 32768 + (wn + rsel) * 128;
    int kb = (kb0 + ks * 64) ^ kx;
    s8v a0 = *(const s8v*)(Ab + kb);
    s8v a1 = *(const s8v*)(Ab + 2048 + kb);
    s8v a2 = *(const s8v*)(Ab + 4096 + kb);
    s8v a3 = *(const s8v*)(Ab + 6144 + kb);
    s8v q0 = *(const s8v*)(Bb + kb);
    s8v q1 = *(const s8v*)(Bb + 2048 + kb);
    __builtin_amdgcn_s_setprio(1);
    acc[0][0] = __builtin_amdgcn_mfma_f32_16x16x32_bf16(q0, a0, acc[0][0], 0, 0, 0);
    acc[0][1] = __builtin_amdgcn_mfma_f32_16x16x32_bf16(q1, a0, acc[0][1], 0, 0, 0);
    acc[1][0] = __builtin_amdgcn_mfma_f32_16x16x32_bf16(q0, a1, acc[1][0], 0, 0, 0);
    acc[1][1] = __builtin_amdgcn_mfma_f32_16x16x32_bf16(q1, a1, acc[1][1], 0, 0, 0);
    acc[2][0] = __builtin_amdgcn_mfma_f32_16x16x32_bf16(q0, a2, acc[2][0], 0, 0, 0);
    acc[2][1] = __builtin_amdgcn_mfma_f32_16x16x32_bf16(q1, a2, acc[2][1], 0, 0, 0);
    acc[3][0] = __builtin_amdgcn_mfma_f32_16x16x32_bf16(q0, a3, acc[3][0], 0, 0, 0);
    acc[3][1] = __builtin_amdgcn_mfma_f32_16x16x32_bf16(q1, a3, acc[3][1], 0, 0, 0);
    __builtin_amdgcn_s_setprio(0);
  };

  stage(bf0, 0);
  for (int t = 0; t < nk - 1; ++t) {
    stage(bf1, t + 1);
    asm volatile("s_waitcnt vmcnt(5)" ::: "memory");
    __builtin_amdgcn_s_barrier();
    __builtin_amdgcn_sched_barrier(0);
    phase(bf0, 0);
    phase(bf0, 1);
    __builtin_amdgcn_s_barrier();
    char* tp = bf0; bf0 = bf1; bf1 = tp;
  }
  asm volatile("s_waitcnt vmcnt(0)" ::: "memory");
  __builtin_amdgcn_s_barrier();
  __builtin_amdgcn_sched_barrier(0);
  phase(bf0, 0);
  phase(bf0, 1);

  // epilogue: acc -> LDS 256x64 f32 (swizzled, 64KB) -> nt f4 streams
  float* E = (float*)lds;
  __syncthreads();
#pragma unroll
  for (int i = 0; i < 4; ++i) {
    int lr = wm + i * 16 + rsel;
    int sw = (lr & 7) << 2;
#pragma unroll
    for (int j = 0; j < 2; ++j) {
      int col = wn + j * 16 + ((lane >> 4) << 2);
      *(f4*)&E[lr * 64 + (col ^ sw)] = acc[i][j];
    }
  }
  __syncthreads();
#pragma unroll
  for (int p = 0; p < 8; ++p) {
    int fi = p * 512 + tid;
    int row = fi >> 4, c4 = fi & 15;
    f4 v = *(const f4*)&E[row * 64 + ((c4 ^ (row & 7)) << 2)];
    int rr = bm0 + row;
    int col = bn0 + c4 * 4;
    v[0] += bias[col]; v[1] += bias[col+1]; v[2] += bias[col+2]; v[3] += bias[col+3];
    __builtin_nontemporal_store(v, (f4*)(C + (size_t)rr * ldc + col));
  }
}

// 64x64 tile transpose: f32 (rows, cols) -> bf16 (cols, rows)
__device__ __forceinline__ void wtrans_tile(const float* src, unsigned short* dst,
                                            int rows, int cols, int c0, int r0) {
  __shared__ float t[64][65];
  int tx = threadIdx.x & 63, ty = threadIdx.x >> 6;
#pragma unroll
  for (int j = 0; j < 16; ++j) {
    int r = j * 4 + ty;
    t[r][tx] = src[(size_t)(r0 + r) * cols + c0 + tx];
  }
  __syncthreads();
#pragma unroll
  for (int j = 0; j < 16; ++j) {
    int n = j * 4 + ty;
    dst[(size_t)(c0 + n) * rows + r0 + tx] = (unsigned short)f2bf(t[tx][n]);
  }
}

__global__ __launch_bounds__(256) void wtrans_k(const float* __restrict__ src,
                                                unsigned short* __restrict__ dst,
                                                int rows, int cols) {
  wtrans_tile(src, dst, rows, cols, blockIdx.x * 64, blockIdx.y * 64);
}

// All 42 H x H weight transposes in one launch. z = l*7 + wi.
__global__ __launch_bounds__(256) void wtrans_all_k(
    const float* __restrict__ w0, const float* __restrict__ w1,
    const float* __restrict__ w2, const float* __restrict__ w3,
    const float* __restrict__ w4, const float* __restrict__ w5,
    const float* __restrict__ w6, unsigned short* __restrict__ dst) {
  int z = blockIdx.z;
  int l = z / 7, wi = z % 7;
  const float* src;
  switch (wi) {
    case 0: src = w0; break;
    case 1: src = w1; break;
    case 2: src = w2; break;
    case 3: src = w3; break;
    case 4: src = w4; break;
    case 5: src = w5; break;
    default: src = w6; break;
  }
  src += (size_t)l * 1024 * 1024;
  unsigned short* d = dst + (size_t)z * 1024 * 1024;
  wtrans_tile(src, d, 1024, 1024, blockIdx.x * 64, blockIdx.y * 64);
}

__global__ __launch_bounds__(256) void convbf_k(const float* __restrict__ src,
                                                unsigned short* __restrict__ dst, int n4) {
  int i = blockIdx.x * 256 + threadIdx.x;
  if (i >= n4) return;
  f4 f = ((const f4*)src)[i];
  s4v v;
  v[0] = f2bf(f[0]); v[1] = f2bf(f[1]); v[2] = f2bf(f[2]); v[3] = f2bf(f[3]);
  ((s4v*)dst)[i] = v;
}

// Concatenated bias buffers: catb[l] = [bq_s|bk_s|bv_s] (3072), catbc[l] = [bk_c|bv_c] (2048)
__global__ __launch_bounds__(1024) void catb_k(
    const float* __restrict__ bq, const float* __restrict__ bk,
    const float* __restrict__ bv, const float* __restrict__ bkc,
    const float* __restrict__ bvc, float* __restrict__ catb,
    float* __restrict__ catbc) {
  int l = blockIdx.x, t = threadIdx.x;
  size_t o = (size_t)l * 1024 + t;
  catb[(size_t)l * 3072 + t] = bq[o];
  catb[(size_t)l * 3072 + 1024 + t] = bk[o];
  catb[(size_t)l * 3072 + 2048 + t] = bv[o];
  catbc[(size_t)l * 2048 + t] = bkc[o];
  catbc[(size_t)l * 2048 + 1024 + t] = bvc[o];
}

// ---------------------------------------------------------------------------
// Fused softmax + transpose, 32 q-rows per block, 512 threads.
// ---------------------------------------------------------------------------
template<int CAUSAL>
__global__ __launch_bounds__(512) void smt_k(const float* __restrict__ Sf,
                                             float* __restrict__ outT,
                                             unsigned short* __restrict__ Wb) {
  __shared__ float T[32][524];
  int b = blockIdx.y;
  int q0 = blockIdx.x * 32;
  int t = threadIdx.x;
  const float* Sp = Sf + ((size_t)b * 512 + q0) * 512;
#pragma unroll
  for (int j = 0; j < 8; ++j) {
    int idx = t + 512 * j;
    int r = idx >> 7, c4 = idx & 127;
    f4 v = *(const f4*)(Sp + (size_t)r * 512 + c4 * 4);
    *(f4*)&T[r][c4 * 4] = v;
  }
  __syncthreads();
  int w = t >> 6, l = t & 63;
  int r = 4 * w + (l >> 4);
  int l16 = l & 15;
  int q = q0 + r;
  const float scale = 0.03125f;
  float v[32];
#pragma unroll
  for (int j = 0; j < 32; ++j) {
    int k = l16 + 16 * j;
    float x = T[r][k] * scale;
    if (CAUSAL && k > q) x += -1.0e7f;
    v[j] = x;
  }
  float m = v[0];
#pragma unroll
  for (int j = 1; j < 32; ++j) m = fmaxf(m, v[j]);
  m = fmaxf(m, __shfl_xor(m, 1)); m = fmaxf(m, __shfl_xor(m, 2));
  m = fmaxf(m, __shfl_xor(m, 4)); m = fmaxf(m, __shfl_xor(m, 8));
  float s = 0.f;
#pragma unroll
  for (int j = 0; j < 32; ++j) { v[j] = __expf(v[j] - m); s += v[j]; }
  s += __shfl_xor(s, 1); s += __shfl_xor(s, 2);
  s += __shfl_xor(s, 4); s += __shfl_xor(s, 8);
  float inv = 1.0f / s;
#pragma unroll
  for (int j = 0; j < 32; ++j) T[r][l16 + 16 * j] = v[j] * inv;
  __syncthreads();
  float* op = outT + (size_t)b * 512 * 512 + q0;
  int ql = t & 31, kb = t >> 5;
#pragma unroll
  for (int i = 0; i < 32; ++i) {
    int k = kb + 16 * i;
    __builtin_nontemporal_store(T[ql][k], &op[(size_t)k * 512 + ql]);
  }
  unsigned short* wp = Wb + ((size_t)b * 512 + q0) * 512;
#pragma unroll
  for (int i = 0; i < 4; ++i) {
    int rr = 4 * w + i;
    const float* row = &T[rr][l * 8];
    s8v o;
#pragma unroll
    for (int j = 0; j < 8; ++j) o[j] = f2bf(row[j]);
    *(s8v*)(wp + (size_t)rr * 512 + l * 8) = o;
  }
}

__global__ __launch_bounds__(256) void embed_pe_k(const int* __restrict__ ids,
                                                  const float* __restrict__ emb,
                                                  float* __restrict__ ctx,
                                                  unsigned short* __restrict__ ctxb) {
  int row = blockIdx.x;
  int s = row & 511;
  int t = threadIdx.x;
  int id = ids[row];
  f4 e = *(const f4*)(emb + (size_t)id * 1024 + t * 4);
  int j0 = 2 * t, j1 = 2 * t + 1;
  float fr0 = powf(10000.0f, -2.0f * (float)j0 / 1024.0f);
  float fr1 = powf(10000.0f, -2.0f * (float)j1 / 1024.0f);
  float s0, c0, s1, c1;
  sincosf((float)s * fr0, &s0, &c0);
  sincosf((float)s * fr1, &s1, &c1);
  f4 o;
  o[0] = e[0] + s0; o[1] = e[1] + c0; o[2] = e[2] + s1; o[3] = e[3] + c1;
  *(f4*)(ctx + (size_t)row * 1024 + t * 4) = o;
  s4v ob;
  ob[0] = f2bf(o[0]); ob[1] = f2bf(o[1]); ob[2] = f2bf(o[2]); ob[3] = f2bf(o[3]);
  *(s4v*)(ctxb + (size_t)row * 1024 + t * 4) = ob;
}

extern "C" void kernel_launch(void* const* d_in, const int* in_sizes, int n_in,
                              void* d_out, int out_size, void* d_ws, size_t ws_size,
                              hipStream_t stream) {
  const int B = 8, S = 512, H = 1024, V = 32000, L = 6;
  const int M = B * S;  // 4096

  const int* ids = (const int*)d_in[0];
  const float* ann = (const float*)d_in[1];
  const float* emb = (const float*)d_in[3];
  const float* bq_s = (const float*)d_in[5];
  const float* bk_s = (const float*)d_in[7];
  const float* bv_s = (const float*)d_in[9];
  const float* bq_c = (const float*)d_in[11];
  const float* bk_c = (const float*)d_in[13];
  const float* bv_c = (const float*)d_in[15];
  const float* bm = (const float*)d_in[17];
  const float* Wout = (const float*)d_in[18];
  const float* bout = (const float*)d_in[19];
  float* out = (float*)d_out;

  char* ws = (char*)d_ws;
  if (ws_size < ((size_t)164 << 20)) return;
  float* X0 = (float*)ws;                                             // 16MB residual (in-place)
  unsigned short* Xs0 = (unsigned short*)(ws + ((size_t)16 << 20));   // 8MB bf16 ctx slot 0
  unsigned short* Xs1 = (unsigned short*)(ws + ((size_t)24 << 20));   // 8MB bf16 ctx slot 1
  unsigned short* QKbf = (unsigned short*)(ws + ((size_t)32 << 20));  // 16MB (4096,2048)
  unsigned short* Vtbf = (unsigned short*)(ws + ((size_t)48 << 20));  // 8MB (H,4096)
  float* Sbuf = (float*)(ws + ((size_t)56 << 20));                    // 8MB raw scores f32
  unsigned short* Wbf = (unsigned short*)(ws + ((size_t)64 << 20));   // 4MB softmax bf16
  unsigned short* annbf = (unsigned short*)(ws + ((size_t)68 << 20)); // 8MB
  unsigned short* WT = (unsigned short*)(ws + ((size_t)76 << 20));    // 84MB: 42 x (H,H)
  float* catb = (float*)(ws + ((size_t)160 << 20));                   // 72KB (L,3072)
  float* catbc = (float*)(ws + ((size_t)160 << 20) + (96 << 10));     // 48KB (L,2048)
  unsigned short* KcAll = (unsigned short*)d_out;                     // 48MB: 6 x (4096,H)
  unsigned short* VtcAll = (unsigned short*)((char*)d_out + ((size_t)48 << 20)); // 48MB

  size_t enc_off = (size_t)M * V;
  size_t self_off = enc_off + (size_t)L * B * S * S;

  long sQ = (long)S * H;
  long sS = (long)S * S;
  const size_t WSZ = (size_t)H * H;
  const long sW7 = (long)(7 * WSZ);

  embed_pe_k<<<M, 256, 0, stream>>>(ids, emb, X0, Xs0);
  convbf_k<<<(M * H / 4 + 255) / 256, 256, 0, stream>>>(ann, annbf, M * H / 4);
  catb_k<<<L, 1024, 0, stream>>>(bq_s, bk_s, bv_s, bk_c, bv_c, catb, catbc);
  wtrans_all_k<<<dim3(16, 16, 42), 256, 0, stream>>>(
      (const float*)d_in[4], (const float*)d_in[6], (const float*)d_in[8],
      (const float*)d_in[10], (const float*)d_in[12], (const float*)d_in[14],
      (const float*)d_in[16], WT);
  // All-layer cross K|V^T in one launch: (l, 4096, 2048); cols >= 1024 -> VtcAll^T
  gemmp<1, 0, 0, 0, 1, 1><<<dim3(16, 32, 6), 256, 0, stream>>>(
      annbf, WT + 4 * WSZ, catbc, nullptr, nullptr,
      nullptr, KcAll, VtcAll, 1024, M,
      H, H, 0, H, 0, 16,
      0, sW7, 0, (long)M * H, 0, 2048, (long)H * M);

  unsigned short* Xa = Xs0;
  unsigned short* Xb = Xs1;

  for (int l = 0; l < L; ++l) {
    size_t bo = (size_t)l * H;
    unsigned short* WTl = WT + (size_t)l * 7 * WSZ;

    // ---- self attention ----
    // Q|K|V = X @ [Wq Wk Wv] : (4096, 3072); V-cols written transposed -> Vtbf
    gemmp<1, 0, 0, 0, 1, 1><<<dim3(24, 32), 256, 0, stream>>>(
        Xa, WTl, catb + (size_t)l * 3072, nullptr, nullptr,
        nullptr, QKbf, Vtbf, 2048, M,
        H, H, 0, 2048, 0, 16,
        0, 0, 0, 0, 0, 0, 0);
    // raw scores (b,q,k) -> Sbuf
    gemm64<0, 1, 0><<<dim3(8, 8, B), 256, 0, stream>>>(
        QKbf, QKbf + 1024, nullptr, Sbuf, nullptr,
        2048, 2048, S, 0, 0, 16, (long)S * 2048, (long)S * 2048, sS, 0, 0);
    smt_k<1><<<dim3(16, B), 512, 0, stream>>>(
        Sbuf, out + self_off + (size_t)l * B * S * S, Wbf);
    // R1 = X0 + W @ V (in-place f32) ; bf16 -> Xb
    gemm64<1, 1, 1><<<dim3(16, 8, B), 256, 0, stream>>>(
        Wbf, Vtbf, X0, X0, Xb,
        S, M, H, H, H, 8, sS, 512, sQ, sQ, sQ);
    // ---- cross attention ----
    gemmp<1, 0, 0, 0, 1, 0><<<dim3(8, 32), 256, 0, stream>>>(
        Xb, WTl + 3 * WSZ, bq_c + bo, nullptr, nullptr,
        nullptr, QKbf, nullptr, 0, 0,
        H, H, 0, 1024, 0, 16,
        0, 0, 0, 0, 0, 0, 0);
    gemm64<0, 1, 0><<<dim3(8, 8, B), 256, 0, stream>>>(
        QKbf, KcAll + (size_t)l * M * H, nullptr, Sbuf, nullptr,
        1024, 1024, S, 0, 0, 16, (long)S * 1024, (long)S * 1024, sS, 0, 0);
    smt_k<0><<<dim3(16, B), 512, 0, stream>>>(
        Sbuf, out + enc_off + (size_t)l * B * S * S, Wbf);
    // R2 = R1 + W @ V (in-place f32) ; bf16 -> Xa
    gemm64<1, 1, 1><<<dim3(16, 8, B), 256, 0, stream>>>(
        Wbf, VtcAll + (size_t)l * H * M, X0, X0, Xa,
        S, M, H, H, H, 8, sS, 512, sQ, sQ, sQ);
    // ctx' = R2 + relu(R2 @ Wm + bm) (in-place f32) ; bf16 -> Xb
    gemmp<1, 1, 1, 1, 1, 0><<<dim3(8, 32), 256, 0, stream>>>(
        Xa, WTl + 6 * WSZ, bm + bo, nullptr, X0,
        X0, Xb, nullptr, 0, 0,
        H, H, H, H, H, 16,
        0, 0, 0, 0, 0, 0, 0);
    unsigned short* tb = Xa; Xa = Xb; Xb = tb;
  }

  // WoutT (V, H) bf16 -> overlay WT region (weights no longer needed)
  wtrans_k<<<dim3(V / 64, H / 64), 256, 0, stream>>>(Wout, WT, H, V);
  // logits = ctx @ Wout + bout   (BM=256xBN=64, 2 blocks/CU, nt-store epilogue)
  gemm_logits<<<dim3(500, 16), 512, 0, stream>>>(Xa, WT, bout, out);
}